// Round 4
// baseline (2757.708 us; speedup 1.0000x reference)
//
#include <hip/hip_runtime.h>
#include <cstdint>
#include <cstddef>

#define NN 1024
#define EE 2048
#define ETOT 3072
#define HH 32

// ---------------- utility ----------------
__global__ void k_zero_int(int* p, int n) {
    int i = blockIdx.x * 256 + threadIdx.x;
    if (i < n) p[i] = 0;
}

// Detect int32 vs int64 edge_index: odd int32 words are all-zero iff int64.
__global__ void k_detect(const int* ei, int* flag) {
    int i = blockIdx.x * 256 + threadIdx.x;
    int idx = 2 * i + 1;
    if (idx < 2 * EE && ei[idx] != 0) atomicOr(flag, 1);
}

__global__ void k_edge_prep(const int* ei, const int* flag, int* srcA, int* dstA, int* cnt) {
    int e = blockIdx.x * 256 + threadIdx.x;
    if (e >= ETOT) return;
    int s, d;
    if (e < EE) {
        if (*flag) { s = ei[e]; d = ei[EE + e]; }
        else       { s = ei[2 * e]; d = ei[2 * (EE + e)]; }
        s &= (NN - 1); d &= (NN - 1);
    } else {
        s = d = e - EE;
    }
    srcA[e] = s; dstA[e] = d;
    atomicAdd(&cnt[d], 1);
}

__global__ void k_scan(const int* cnt, int* off) {
    __shared__ int sh[NN];
    int t = threadIdx.x;
    sh[t] = cnt[t];
    __syncthreads();
    for (int o = 1; o < NN; o <<= 1) {
        int v = (t >= o) ? sh[t - o] : 0;
        __syncthreads();
        sh[t] += v;
        __syncthreads();
    }
    off[t + 1] = sh[t];
    if (t == 0) off[0] = 0;
}

__global__ void k_fill(const int* dstA, const int* off, int* cur, int* csre) {
    int e = blockIdx.x * 256 + threadIdx.x;
    if (e >= ETOT) return;
    int d = dstA[e];
    int p = atomicAdd(&cur[d], 1);
    csre[off[d] + p] = e;
}

// ------- fp32 GEMM: C[M,Nsub] = A[M,K] @ B[K, ldb-strided cols] + bias -------
// 64x64 tile, 256 threads, 4x4 per thread, BK=16.
#define TM 64
#define TN 64
#define TK 16
__global__ __launch_bounds__(256) void k_gemm(
        const float* __restrict__ A, const float* __restrict__ B,
        const float* __restrict__ bias, float* __restrict__ Cm,
        int M, int Nsub, int K, int ldb, int act) {
    __shared__ float As[TK][TM];
    __shared__ float Bs[TK][TN];
    int tid = threadIdx.x;
    int tx = tid % 16, ty = tid / 16;
    int m0 = blockIdx.y * TM, n0 = blockIdx.x * TN;
    float acc[4][4] = {};
    for (int k0 = 0; k0 < K; k0 += TK) {
#pragma unroll
        for (int i = 0; i < 4; ++i) {
            int idx = tid * 4 + i;           // A: m = idx/16, k = idx%16
            int m = idx >> 4, k = idx & 15;
            float v = 0.f;
            if (k0 + k < K && m0 + m < M) v = A[(size_t)(m0 + m) * K + k0 + k];
            As[k][m] = v;
        }
#pragma unroll
        for (int i = 0; i < 4; ++i) {
            int idx = tid * 4 + i;           // B: k = idx/64, n = idx%64
            int k = idx >> 6, n = idx & 63;
            float v = 0.f;
            if (k0 + k < K && n0 + n < Nsub) v = B[(size_t)(k0 + k) * ldb + n0 + n];
            Bs[k][n] = v;
        }
        __syncthreads();
#pragma unroll
        for (int kk = 0; kk < TK; ++kk) {
            float4 a4 = *(const float4*)&As[kk][ty * 4];
            float4 b4 = *(const float4*)&Bs[kk][tx * 4];
            float af[4] = {a4.x, a4.y, a4.z, a4.w};
            float bf[4] = {b4.x, b4.y, b4.z, b4.w};
#pragma unroll
            for (int i = 0; i < 4; ++i)
#pragma unroll
                for (int j = 0; j < 4; ++j)
                    acc[i][j] += af[i] * bf[j];
        }
        __syncthreads();
    }
#pragma unroll
    for (int i = 0; i < 4; ++i) {
        int m = m0 + ty * 4 + i;
        if (m >= M) continue;
#pragma unroll
        for (int j = 0; j < 4; ++j) {
            int n = n0 + tx * 4 + j;          // n is the sub-matrix column index
            if (n < Nsub) {
                float v = acc[i][j] + bias[n];   // FIXED: was bias[n0 + n]
                if (act && v < 0.f) v *= 0.01f;
                Cm[(size_t)m * Nsub + n] = v;
            }
        }
    }
}

// ---------------- naive GEMM for tiny final layer ----------------
__global__ void k_gemm_naive(const float* __restrict__ A, const float* __restrict__ B,
                             const float* __restrict__ bias, float* __restrict__ out,
                             int M, int N, int K, int act) {
    int idx = blockIdx.x * 256 + threadIdx.x;
    if (idx >= M * N) return;
    int m = idx / N, n = idx % N;
    float s = bias[n];
    for (int k = 0; k < K; ++k)
        s += A[(size_t)m * K + k] * B[(size_t)k * N + n];
    if (act && s < 0.f) s *= 0.01f;
    out[idx] = s;
}

// ---------------- attention scores: one wave per (edge, local head) -----------
__global__ void k_score(const float* __restrict__ xl, const float* __restrict__ xr,
                        const float* __restrict__ att, const int* __restrict__ srcA,
                        const int* __restrict__ dstA, float* __restrict__ sc,
                        int C, int HG, int h0) {
    int wid = (blockIdx.x * 256 + threadIdx.x) >> 6;
    int lane = threadIdx.x & 63;
    if (wid >= ETOT * HG) return;
    int e = wid / HG, hl = wid % HG;
    int s = srcA[e], d = dstA[e];
    const float* pl = xl + ((size_t)s * HG + hl) * C;
    const float* pr = xr + ((size_t)d * HG + hl) * C;
    const float* pa = att + (size_t)(h0 + hl) * C;
    float acc = 0.f;
    for (int c = lane; c < C; c += 64) {
        float v = pl[c] + pr[c];
        v = v > 0.f ? v : 0.2f * v;
        acc += v * pa[c];
    }
#pragma unroll
    for (int off = 32; off; off >>= 1) acc += __shfl_down(acc, off, 64);
    if (lane == 0) sc[(size_t)e * HH + h0 + hl] = acc;
}

// ---------------- softmax per (dst, head) over incoming edges -----------------
__global__ void k_softmax(const int* __restrict__ off, const int* __restrict__ csre,
                          float* __restrict__ sc, int HG, int h0) {
    int idx = blockIdx.x * 256 + threadIdx.x;
    if (idx >= NN * HG) return;
    int d = idx / HG, h = h0 + idx % HG;
    int b = off[d], en = off[d + 1];
    float m = -1e30f;
    for (int i = b; i < en; ++i) m = fmaxf(m, sc[(size_t)csre[i] * HH + h]);
    float ssum = 0.f;
    for (int i = b; i < en; ++i) ssum += expf(sc[(size_t)csre[i] * HH + h] - m);
    float inv = 1.f / ssum;
    for (int i = b; i < en; ++i) {
        size_t p = (size_t)csre[i] * HH + h;
        sc[p] = expf(sc[p] - m) * inv;
    }
}

// ---------------- aggregate head-group partial sums into z --------------------
__global__ void k_aggregate(const float* __restrict__ xl, const float* __restrict__ sc,
                            const int* __restrict__ off, const int* __restrict__ csre,
                            const int* __restrict__ srcA, const float* __restrict__ bias,
                            float* __restrict__ z, int C, int HG, int h0,
                            int first, int last, int act) {
    int d = blockIdx.x;
    int c = blockIdx.y * 256 + threadIdx.x;
    if (c >= C) return;
    float acc = 0.f;
    int b = off[d], en = off[d + 1];
    for (int i = b; i < en; ++i) {
        int e = csre[i];
        int s = srcA[e];
        const float* pl = xl + (size_t)s * HG * C + c;
        const float* pa = sc + (size_t)e * HH + h0;
        for (int hl = 0; hl < HG; ++hl)
            acc += pa[hl] * pl[(size_t)hl * C];
    }
    if (!first) acc += z[(size_t)d * C + c];
    if (last) {
        acc = acc * (1.f / 32.f) + bias[c];
        if (act && acc < 0.f) acc *= 0.01f;
    }
    z[(size_t)d * C + c] = acc;
}

// ---------------- host ----------------
extern "C" void kernel_launch(void* const* d_in, const int* in_sizes, int n_in,
                              void* d_out, int out_size, void* d_ws, size_t ws_size,
                              hipStream_t stream) {
    const float* x   = (const float*)d_in[0];
    const int* ei    = (const int*)d_in[1];
    const float* w1l = (const float*)d_in[2];  const float* b1l = (const float*)d_in[3];
    const float* w1r = (const float*)d_in[4];  const float* b1r = (const float*)d_in[5];
    const float* att1= (const float*)d_in[6];  const float* gb1 = (const float*)d_in[7];
    const float* w2l = (const float*)d_in[8];  const float* b2l = (const float*)d_in[9];
    const float* w2r = (const float*)d_in[10]; const float* b2r = (const float*)d_in[11];
    const float* att2= (const float*)d_in[12]; const float* gb2 = (const float*)d_in[13];
    const float* w3l = (const float*)d_in[14]; const float* b3l = (const float*)d_in[15];
    const float* w3r = (const float*)d_in[16]; const float* b3r = (const float*)d_in[17];
    const float* att3= (const float*)d_in[18]; const float* gb3 = (const float*)d_in[19];
    const float* dw1 = (const float*)d_in[20]; const float* db1 = (const float*)d_in[21];
    const float* dw2 = (const float*)d_in[22]; const float* db2 = (const float*)d_in[23];
    const float* dw3 = (const float*)d_in[24]; const float* db3 = (const float*)d_in[25];
    float* outp = (float*)d_out;

    // ---- workspace carve-out (256B aligned) ----
    char* p = (char*)d_ws;
    auto alloc = [&](size_t bytes) -> char* {
        char* r = p;
        p += (bytes + 255) & ~(size_t)255;
        return r;
    };
    float* sc   = (float*)alloc((size_t)ETOT * HH * 4);
    float* za   = (float*)alloc((size_t)NN * 1028 * 4);
    float* zb   = (float*)alloc((size_t)NN * 1028 * 4);
    int*   ints = (int*)  alloc((size_t)(2 * NN + 16) * 4);
    int* cnt  = ints;
    int* cur  = ints + NN;
    int* flag = ints + 2 * NN;
    int* offp = (int*)alloc((size_t)(NN + 1) * 4);
    int* csre = (int*)alloc((size_t)ETOT * 4);
    int* srcA = (int*)alloc((size_t)ETOT * 4);
    int* dstA = (int*)alloc((size_t)ETOT * 4);
    size_t used = (size_t)(p - (char*)d_ws);
    size_t remain = (ws_size > used) ? (ws_size - used) : 0;
    float* chunk = (float*)p;

    // ---- CSR build ----
    k_zero_int<<<dim3((2 * NN + 16 + 255) / 256), dim3(256), 0, stream>>>(ints, 2 * NN + 16);
    k_detect<<<dim3((EE + 255) / 256), dim3(256), 0, stream>>>(ei, flag);
    k_edge_prep<<<dim3((ETOT + 255) / 256), dim3(256), 0, stream>>>(ei, flag, srcA, dstA, cnt);
    k_scan<<<dim3(1), dim3(NN), 0, stream>>>(cnt, offp);
    k_fill<<<dim3((ETOT + 255) / 256), dim3(256), 0, stream>>>(dstA, offp, cur, csre);

    struct Layer {
        const float* in; int cin; int C;
        const float *wl, *bl, *wr, *br, *att, *gb;
        float* zout; int act;
    };
    Layer L[3] = {
        { x,    4, 128,  w1l, b1l, w1r, b1r, att1, gb1, za, 1 },
        { za, 128, 512,  w2l, b2l, w2r, b2r, att2, gb2, zb, 1 },
        { zb, 512, 1028, w3l, b3l, w3r, b3r, att3, gb3, za, 0 },
    };

    for (int li = 0; li < 3; ++li) {
        int C = L[li].C, K = L[li].cin;
        int HG = 32;
        while (HG > 1 && 2 * (size_t)NN * HG * C * 4 + 1024 > remain) HG >>= 1;
        int nchunk = HH / HG;
        size_t chunkElems = (size_t)NN * HG * C;
        float* xlc = chunk;
        float* xrc = chunk + ((chunkElems + 63) & ~(size_t)63);
        for (int hg = 0; hg < nchunk; ++hg) {
            int h0 = hg * HG;
            int colOff = h0 * C;
            int Nsub = HG * C;
            dim3 gg((Nsub + TN - 1) / TN, (NN + TM - 1) / TM);
            k_gemm<<<gg, dim3(256), 0, stream>>>(L[li].in, L[li].wl + colOff, L[li].bl + colOff,
                                                 xlc, NN, Nsub, K, HH * C, 0);
            k_gemm<<<gg, dim3(256), 0, stream>>>(L[li].in, L[li].wr + colOff, L[li].br + colOff,
                                                 xrc, NN, Nsub, K, HH * C, 0);
            int waves = ETOT * HG;
            k_score<<<dim3((waves * 64 + 255) / 256), dim3(256), 0, stream>>>(
                xlc, xrc, L[li].att, srcA, dstA, sc, C, HG, h0);
            k_softmax<<<dim3((NN * HG + 255) / 256), dim3(256), 0, stream>>>(offp, csre, sc, HG, h0);
            dim3 ga(NN, (C + 255) / 256);
            k_aggregate<<<ga, dim3(256), 0, stream>>>(xlc, sc, offp, csre, srcA, L[li].gb,
                                                      L[li].zout, C, HG, h0,
                                                      hg == 0, hg == nchunk - 1, L[li].act);
        }
    }

    // decoder
    k_gemm<<<dim3(512 / TN, NN / TM), dim3(256), 0, stream>>>(za, dw1, db1, zb, NN, 512, 1028, 512, 1);
    k_gemm<<<dim3(128 / TN, NN / TM), dim3(256), 0, stream>>>(zb, dw2, db2, za, NN, 128, 512, 128, 1);
    k_gemm_naive<<<dim3((NN * 2 + 255) / 256), dim3(256), 0, stream>>>(za, dw3, db3, outp, NN, 2, 128, 0);
}

// Round 5
// 1206.606 us; speedup vs baseline: 2.2855x; 2.2855x over previous
//
#include <hip/hip_runtime.h>
#include <cstdint>
#include <cstddef>

#define NN 1024
#define EE 2048
#define ETOT 3072
#define HH 32

typedef __bf16 bf16_t;
typedef __attribute__((ext_vector_type(8))) __bf16 bf16x8;
typedef __attribute__((ext_vector_type(4))) float f32x4;

// ---------------- utility ----------------
__global__ void k_zero_int(int* p, int n) {
    int i = blockIdx.x * 256 + threadIdx.x;
    if (i < n) p[i] = 0;
}

// Detect int32 vs int64 edge_index: odd int32 words are all-zero iff int64.
__global__ void k_detect(const int* ei, int* flag) {
    int i = blockIdx.x * 256 + threadIdx.x;
    int idx = 2 * i + 1;
    if (idx < 2 * EE && ei[idx] != 0) atomicOr(flag, 1);
}

__global__ void k_edge_prep(const int* ei, const int* flag, int* srcA, int* dstA, int* cnt) {
    int e = blockIdx.x * 256 + threadIdx.x;
    if (e >= ETOT) return;
    int s, d;
    if (e < EE) {
        if (*flag) { s = ei[e]; d = ei[EE + e]; }
        else       { s = ei[2 * e]; d = ei[2 * (EE + e)]; }
        s &= (NN - 1); d &= (NN - 1);
    } else {
        s = d = e - EE;
    }
    srcA[e] = s; dstA[e] = d;
    atomicAdd(&cnt[d], 1);
}

__global__ void k_scan(const int* cnt, int* off) {
    __shared__ int sh[NN];
    int t = threadIdx.x;
    sh[t] = cnt[t];
    __syncthreads();
    for (int o = 1; o < NN; o <<= 1) {
        int v = (t >= o) ? sh[t - o] : 0;
        __syncthreads();
        sh[t] += v;
        __syncthreads();
    }
    off[t + 1] = sh[t];
    if (t == 0) off[0] = 0;
}

__global__ void k_fill(const int* dstA, const int* off, int* cur, int* csre) {
    int e = blockIdx.x * 256 + threadIdx.x;
    if (e >= ETOT) return;
    int d = dstA[e];
    int p = atomicAdd(&cur[d], 1);
    csre[off[d] + p] = e;
}

// ---------------- fp32 -> bf16 converts ----------------
// A [M x K] fp32 row-major -> Ab [M x Kp] bf16 (zero pad K..Kp)
__global__ void k_convA(const float* __restrict__ A, bf16_t* __restrict__ Ab,
                        int M, int K, int Kp) {
    int idx = blockIdx.x * 256 + threadIdx.x;
    if (idx >= M * Kp) return;
    int m = idx / Kp, k = idx % Kp;
    Ab[idx] = (k < K) ? (bf16_t)A[(size_t)m * K + k] : (bf16_t)0.f;
}

// B [K x Nsub] (row stride ldb) fp32 -> Bt [Nsub x Kp] bf16 transposed, zero pad
__global__ void k_convB(const float* __restrict__ B, bf16_t* __restrict__ Bt,
                        int K, int Nsub, int ldb, int Kp) {
    __shared__ float sh[32][33];
    int kt = blockIdx.y * 32, nt = blockIdx.x * 32;
    int tx = threadIdx.x % 32, ty = threadIdx.x / 32;   // 32 x 8
#pragma unroll
    for (int i = 0; i < 4; ++i) {
        int k = kt + ty + i * 8, n = nt + tx;
        sh[ty + i * 8][tx] = (k < K && n < Nsub) ? B[(size_t)k * ldb + n] : 0.f;
    }
    __syncthreads();
#pragma unroll
    for (int i = 0; i < 4; ++i) {
        int n = nt + ty + i * 8, k = kt + tx;
        if (n < Nsub) Bt[(size_t)n * Kp + k] = (bf16_t)sh[tx][ty + i * 8];
    }
}

// ---------------- bf16 MFMA GEMM ----------------
// C[M x Nsub] = Ab[M x Kp] @ Bt[Nsub x Kp]^T + bias; 128x128 tile, 4 waves,
// each wave 64x64 via 4x4 grid of 16x16x32 MFMAs. LDS rows padded to 40 bf16.
#define LDP 40
__global__ __launch_bounds__(256) void k_gemm_bf16(
        const bf16_t* __restrict__ Ab, const bf16_t* __restrict__ Bt,
        const float* __restrict__ bias, float* __restrict__ Cm,
        int M, int Nsub, int Kp, int act) {
    __shared__ bf16_t As[128][LDP];
    __shared__ bf16_t Bs[128][LDP];
    int tid = threadIdx.x;
    int wave = tid >> 6, lane = tid & 63;
    int wm = (wave & 1) * 64, wn = (wave >> 1) * 64;
    int l16 = lane & 15, lq = lane >> 4;
    int m0 = blockIdx.y * 128, n0 = blockIdx.x * 128;

    f32x4 acc[4][4] = {};

    for (int k0 = 0; k0 < Kp; k0 += 32) {
        __syncthreads();
#pragma unroll
        for (int i = 0; i < 2; ++i) {
            int pp = tid + i * 256;          // 512 (row, kchunk) pairs
            int r = pp >> 2, kc = (pp & 3) * 8;
            bf16x8 va = *(const bf16x8*)(Ab + (size_t)(m0 + r) * Kp + k0 + kc);
            *(bf16x8*)(&As[r][kc]) = va;
            bf16x8 vb = {};
            if (n0 + r < Nsub)
                vb = *(const bf16x8*)(Bt + (size_t)(n0 + r) * Kp + k0 + kc);
            *(bf16x8*)(&Bs[r][kc]) = vb;
        }
        __syncthreads();
        bf16x8 af[4], bf[4];
#pragma unroll
        for (int mi = 0; mi < 4; ++mi)
            af[mi] = *(const bf16x8*)(&As[wm + mi * 16 + l16][lq * 8]);
#pragma unroll
        for (int ni = 0; ni < 4; ++ni)
            bf[ni] = *(const bf16x8*)(&Bs[wn + ni * 16 + l16][lq * 8]);
#pragma unroll
        for (int mi = 0; mi < 4; ++mi)
#pragma unroll
            for (int ni = 0; ni < 4; ++ni)
                acc[mi][ni] = __builtin_amdgcn_mfma_f32_16x16x32_bf16(
                    af[mi], bf[ni], acc[mi][ni], 0, 0, 0);
    }
#pragma unroll
    for (int mi = 0; mi < 4; ++mi)
#pragma unroll
        for (int ni = 0; ni < 4; ++ni)
#pragma unroll
            for (int r = 0; r < 4; ++r) {
                int row = m0 + wm + mi * 16 + lq * 4 + r;
                int col = n0 + wn + ni * 16 + l16;
                if (row < M && col < Nsub) {
                    float v = acc[mi][ni][r] + bias[col];
                    if (act && v < 0.f) v *= 0.01f;
                    Cm[(size_t)row * Nsub + col] = v;
                }
            }
}

// ------- fp32 GEMM (layer-1 / decoder-2): 64x64 tile, 4x4/thread, BK=16 -------
#define TM 64
#define TN 64
#define TK 16
__global__ __launch_bounds__(256) void k_gemm(
        const float* __restrict__ A, const float* __restrict__ B,
        const float* __restrict__ bias, float* __restrict__ Cm,
        int M, int Nsub, int K, int ldb, int act) {
    __shared__ float As[TK][TM];
    __shared__ float Bs[TK][TN];
    int tid = threadIdx.x;
    int tx = tid % 16, ty = tid / 16;
    int m0 = blockIdx.y * TM, n0 = blockIdx.x * TN;
    float acc[4][4] = {};
    for (int k0 = 0; k0 < K; k0 += TK) {
#pragma unroll
        for (int i = 0; i < 4; ++i) {
            int idx = tid * 4 + i;
            int m = idx >> 4, k = idx & 15;
            float v = 0.f;
            if (k0 + k < K && m0 + m < M) v = A[(size_t)(m0 + m) * K + k0 + k];
            As[k][m] = v;
        }
#pragma unroll
        for (int i = 0; i < 4; ++i) {
            int idx = tid * 4 + i;
            int k = idx >> 6, n = idx & 63;
            float v = 0.f;
            if (k0 + k < K && n0 + n < Nsub) v = B[(size_t)(k0 + k) * ldb + n0 + n];
            Bs[k][n] = v;
        }
        __syncthreads();
#pragma unroll
        for (int kk = 0; kk < TK; ++kk) {
            float4 a4 = *(const float4*)&As[kk][ty * 4];
            float4 b4 = *(const float4*)&Bs[kk][tx * 4];
            float af[4] = {a4.x, a4.y, a4.z, a4.w};
            float bf[4] = {b4.x, b4.y, b4.z, b4.w};
#pragma unroll
            for (int i = 0; i < 4; ++i)
#pragma unroll
                for (int j = 0; j < 4; ++j)
                    acc[i][j] += af[i] * bf[j];
        }
        __syncthreads();
    }
#pragma unroll
    for (int i = 0; i < 4; ++i) {
        int m = m0 + ty * 4 + i;
        if (m >= M) continue;
#pragma unroll
        for (int j = 0; j < 4; ++j) {
            int n = n0 + tx * 4 + j;
            if (n < Nsub) {
                float v = acc[i][j] + bias[n];
                if (act && v < 0.f) v *= 0.01f;
                Cm[(size_t)m * Nsub + n] = v;
            }
        }
    }
}

// ---------------- naive GEMM for tiny final layer ----------------
__global__ void k_gemm_naive(const float* __restrict__ A, const float* __restrict__ B,
                             const float* __restrict__ bias, float* __restrict__ out,
                             int M, int N, int K, int act) {
    int idx = blockIdx.x * 256 + threadIdx.x;
    if (idx >= M * N) return;
    int m = idx / N, n = idx % N;
    float s = bias[n];
    for (int k = 0; k < K; ++k)
        s += A[(size_t)m * K + k] * B[(size_t)k * N + n];
    if (act && s < 0.f) s *= 0.01f;
    out[idx] = s;
}

// ---------------- attention scores: one wave per (edge, local head) -----------
__global__ void k_score(const float* __restrict__ xl, const float* __restrict__ xr,
                        const float* __restrict__ att, const int* __restrict__ srcA,
                        const int* __restrict__ dstA, float* __restrict__ sc,
                        int C, int HG, int h0) {
    int wid = (blockIdx.x * 256 + threadIdx.x) >> 6;
    int lane = threadIdx.x & 63;
    if (wid >= ETOT * HG) return;
    int e = wid / HG, hl = wid % HG;
    int s = srcA[e], d = dstA[e];
    const float* pl = xl + ((size_t)s * HG + hl) * C;
    const float* pr = xr + ((size_t)d * HG + hl) * C;
    const float* pa = att + (size_t)(h0 + hl) * C;
    float acc = 0.f;
    for (int c = lane; c < C; c += 64) {
        float v = pl[c] + pr[c];
        v = v > 0.f ? v : 0.2f * v;
        acc += v * pa[c];
    }
#pragma unroll
    for (int off = 32; off; off >>= 1) acc += __shfl_down(acc, off, 64);
    if (lane == 0) sc[(size_t)e * HH + h0 + hl] = acc;
}

// ---------------- softmax per (dst, head) over incoming edges -----------------
__global__ void k_softmax(const int* __restrict__ off, const int* __restrict__ csre,
                          float* __restrict__ sc, int HG, int h0) {
    int idx = blockIdx.x * 256 + threadIdx.x;
    if (idx >= NN * HG) return;
    int d = idx / HG, h = h0 + idx % HG;
    int b = off[d], en = off[d + 1];
    float m = -1e30f;
    for (int i = b; i < en; ++i) m = fmaxf(m, sc[(size_t)csre[i] * HH + h]);
    float ssum = 0.f;
    for (int i = b; i < en; ++i) ssum += expf(sc[(size_t)csre[i] * HH + h] - m);
    float inv = 1.f / ssum;
    for (int i = b; i < en; ++i) {
        size_t p = (size_t)csre[i] * HH + h;
        sc[p] = expf(sc[p] - m) * inv;
    }
}

// ---------------- aggregate head-group partial sums into z --------------------
__global__ void k_aggregate(const float* __restrict__ xl, const float* __restrict__ sc,
                            const int* __restrict__ off, const int* __restrict__ csre,
                            const int* __restrict__ srcA, const float* __restrict__ bias,
                            float* __restrict__ z, int C, int HG, int h0,
                            int first, int last, int act) {
    int d = blockIdx.x;
    int c = blockIdx.y * 256 + threadIdx.x;
    if (c >= C) return;
    float acc = 0.f;
    int b = off[d], en = off[d + 1];
    for (int i = b; i < en; ++i) {
        int e = csre[i];
        int s = srcA[e];
        const float* pl = xl + (size_t)s * HG * C + c;
        const float* pa = sc + (size_t)e * HH + h0;
        for (int hl = 0; hl < HG; ++hl)
            acc += pa[hl] * pl[(size_t)hl * C];
    }
    if (!first) acc += z[(size_t)d * C + c];
    if (last) {
        acc = acc * (1.f / 32.f) + bias[c];
        if (act && acc < 0.f) acc *= 0.01f;
    }
    z[(size_t)d * C + c] = acc;
}

// ---------------- host ----------------
extern "C" void kernel_launch(void* const* d_in, const int* in_sizes, int n_in,
                              void* d_out, int out_size, void* d_ws, size_t ws_size,
                              hipStream_t stream) {
    const float* x   = (const float*)d_in[0];
    const int* ei    = (const int*)d_in[1];
    const float* w1l = (const float*)d_in[2];  const float* b1l = (const float*)d_in[3];
    const float* w1r = (const float*)d_in[4];  const float* b1r = (const float*)d_in[5];
    const float* att1= (const float*)d_in[6];  const float* gb1 = (const float*)d_in[7];
    const float* w2l = (const float*)d_in[8];  const float* b2l = (const float*)d_in[9];
    const float* w2r = (const float*)d_in[10]; const float* b2r = (const float*)d_in[11];
    const float* att2= (const float*)d_in[12]; const float* gb2 = (const float*)d_in[13];
    const float* w3l = (const float*)d_in[14]; const float* b3l = (const float*)d_in[15];
    const float* w3r = (const float*)d_in[16]; const float* b3r = (const float*)d_in[17];
    const float* att3= (const float*)d_in[18]; const float* gb3 = (const float*)d_in[19];
    const float* dw1 = (const float*)d_in[20]; const float* db1 = (const float*)d_in[21];
    const float* dw2 = (const float*)d_in[22]; const float* db2 = (const float*)d_in[23];
    const float* dw3 = (const float*)d_in[24]; const float* db3 = (const float*)d_in[25];
    float* outp = (float*)d_out;

    // ---- workspace carve-out (256B aligned) ----
    char* p = (char*)d_ws;
    auto alloc = [&](size_t bytes) -> char* {
        char* r = p;
        p += (bytes + 255) & ~(size_t)255;
        return r;
    };
    float* sc   = (float*)alloc((size_t)ETOT * HH * 4);
    float* za   = (float*)alloc((size_t)NN * 1028 * 4);
    float* zb   = (float*)alloc((size_t)NN * 1028 * 4);
    bf16_t* Abf = (bf16_t*)alloc((size_t)NN * 1056 * 2);   // A in bf16, max Kp=1056
    int*   ints = (int*)  alloc((size_t)(2 * NN + 16) * 4);
    int* cnt  = ints;
    int* cur  = ints + NN;
    int* flag = ints + 2 * NN;
    int* offp = (int*)alloc((size_t)(NN + 1) * 4);
    int* csre = (int*)alloc((size_t)ETOT * 4);
    int* srcA = (int*)alloc((size_t)ETOT * 4);
    int* dstA = (int*)alloc((size_t)ETOT * 4);
    size_t used = (size_t)(p - (char*)d_ws);
    size_t remain = (ws_size > used) ? (ws_size - used) : 0;
    char* chunk = p;

    // ---- CSR build ----
    k_zero_int<<<dim3((2 * NN + 16 + 255) / 256), dim3(256), 0, stream>>>(ints, 2 * NN + 16);
    k_detect<<<dim3((EE + 255) / 256), dim3(256), 0, stream>>>(ei, flag);
    k_edge_prep<<<dim3((ETOT + 255) / 256), dim3(256), 0, stream>>>(ei, flag, srcA, dstA, cnt);
    k_scan<<<dim3(1), dim3(NN), 0, stream>>>(cnt, offp);
    k_fill<<<dim3((ETOT + 255) / 256), dim3(256), 0, stream>>>(dstA, offp, cur, csre);

    struct Layer {
        const float* in; int cin; int C;
        const float *wl, *bl, *wr, *br, *att, *gb;
        float* zout; int act;
    };
    Layer L[3] = {
        { x,    4, 128,  w1l, b1l, w1r, b1r, att1, gb1, za, 1 },
        { za, 128, 512,  w2l, b2l, w2r, b2r, att2, gb2, zb, 1 },
        { zb, 512, 1028, w3l, b3l, w3r, b3r, att3, gb3, za, 0 },
    };
    auto al = [](size_t n) { return (n + 63) & ~(size_t)63; };

    for (int li = 0; li < 3; ++li) {
        int C = L[li].C, K = L[li].cin;
        bool mfma = (K >= 128);
        int Kp = (K + 31) & ~31;
        // per-HG chunk bytes: xl + xr (+ Bt for mfma path)
        size_t perHG = 2ull * NN * C * 4 + (mfma ? (size_t)C * Kp * 2 : 0);
        int HG = 32;
        while (HG > 1 && (size_t)HG * perHG + 8192 > remain) HG >>= 1;
        int nchunk = HH / HG;
        float* xlc = (float*)chunk;
        float* xrc = xlc + al((size_t)NN * HG * C);
        bf16_t* Bt = (bf16_t*)(xrc + al((size_t)NN * HG * C));

        if (mfma)
            k_convA<<<dim3((NN * Kp + 255) / 256), dim3(256), 0, stream>>>(L[li].in, Abf, NN, K, Kp);

        for (int hg = 0; hg < nchunk; ++hg) {
            int h0 = hg * HG;
            int colOff = h0 * C;
            int Nsub = HG * C;
            if (mfma) {
                dim3 gc((Nsub + 31) / 32, Kp / 32);
                dim3 gg((Nsub + 127) / 128, NN / 128);
                k_convB<<<gc, dim3(256), 0, stream>>>(L[li].wl + colOff, Bt, K, Nsub, HH * C, Kp);
                k_gemm_bf16<<<gg, dim3(256), 0, stream>>>(Abf, Bt, L[li].bl + colOff, xlc, NN, Nsub, Kp, 0);
                k_convB<<<gc, dim3(256), 0, stream>>>(L[li].wr + colOff, Bt, K, Nsub, HH * C, Kp);
                k_gemm_bf16<<<gg, dim3(256), 0, stream>>>(Abf, Bt, L[li].br + colOff, xrc, NN, Nsub, Kp, 0);
            } else {
                dim3 gg((Nsub + TN - 1) / TN, (NN + TM - 1) / TM);
                k_gemm<<<gg, dim3(256), 0, stream>>>(L[li].in, L[li].wl + colOff, L[li].bl + colOff,
                                                     xlc, NN, Nsub, K, HH * C, 0);
                k_gemm<<<gg, dim3(256), 0, stream>>>(L[li].in, L[li].wr + colOff, L[li].br + colOff,
                                                     xrc, NN, Nsub, K, HH * C, 0);
            }
            int waves = ETOT * HG;
            k_score<<<dim3((waves * 64 + 255) / 256), dim3(256), 0, stream>>>(
                xlc, xrc, L[li].att, srcA, dstA, sc, C, HG, h0);
            k_softmax<<<dim3((NN * HG + 255) / 256), dim3(256), 0, stream>>>(offp, csre, sc, HG, h0);
            dim3 ga(NN, (C + 255) / 256);
            k_aggregate<<<ga, dim3(256), 0, stream>>>(xlc, sc, offp, csre, srcA, L[li].gb,
                                                      L[li].zout, C, HG, h0,
                                                      hg == 0, hg == nchunk - 1, L[li].act);
        }
    }

    // ---- decoder ----
    // dec1: za[1024x1028] @ dw1[1028x512] + db1, leaky -> zb   (bf16 MFMA, Kp=1056)
    {
        int K = 1028, Kp = 1056, Nsub = 512;
        bf16_t* Bt = (bf16_t*)chunk;
        k_convA<<<dim3((NN * Kp + 255) / 256), dim3(256), 0, stream>>>(za, Abf, NN, K, Kp);
        k_convB<<<dim3(Nsub / 32, Kp / 32), dim3(256), 0, stream>>>(dw1, Bt, K, Nsub, Nsub, Kp);
        k_gemm_bf16<<<dim3(Nsub / 128, NN / 128), dim3(256), 0, stream>>>(Abf, Bt, db1, zb, NN, Nsub, Kp, 1);
    }
    // dec2 + dec3 fp32 (tiny)
    k_gemm<<<dim3(128 / TN, NN / TM), dim3(256), 0, stream>>>(zb, dw2, db2, za, NN, 128, 512, 128, 1);
    k_gemm_naive<<<dim3((NN * 2 + 255) / 256), dim3(256), 0, stream>>>(za, dw3, db3, outp, NN, 2, 128, 0);
}

// Round 6
// 1031.149 us; speedup vs baseline: 2.6744x; 1.1702x over previous
//
#include <hip/hip_runtime.h>
#include <cstdint>
#include <cstddef>

#define NN 1024
#define EE 2048
#define ETOT 3072
#define HH 32

typedef __bf16 bf16_t;
typedef __attribute__((ext_vector_type(8))) __bf16 bf16x8;
typedef __attribute__((ext_vector_type(4))) __bf16 bf16x4;
typedef __attribute__((ext_vector_type(4))) float f32x4;

// ---------------- utility ----------------
__global__ void k_zero_int(int* p, int n) {
    int i = blockIdx.x * 256 + threadIdx.x;
    if (i < n) p[i] = 0;
}

__global__ void k_detect(const int* ei, int* flag) {
    int i = blockIdx.x * 256 + threadIdx.x;
    int idx = 2 * i + 1;
    if (idx < 2 * EE && ei[idx] != 0) atomicOr(flag, 1);
}

__global__ void k_edge_prep(const int* ei, const int* flag, int* srcA, int* dstA, int* cnt) {
    int e = blockIdx.x * 256 + threadIdx.x;
    if (e >= ETOT) return;
    int s, d;
    if (e < EE) {
        if (*flag) { s = ei[e]; d = ei[EE + e]; }
        else       { s = ei[2 * e]; d = ei[2 * (EE + e)]; }
        s &= (NN - 1); d &= (NN - 1);
    } else {
        s = d = e - EE;
    }
    srcA[e] = s; dstA[e] = d;
    atomicAdd(&cnt[d], 1);
}

__global__ void k_scan(const int* cnt, int* off) {
    __shared__ int sh[NN];
    int t = threadIdx.x;
    sh[t] = cnt[t];
    __syncthreads();
    for (int o = 1; o < NN; o <<= 1) {
        int v = (t >= o) ? sh[t - o] : 0;
        __syncthreads();
        sh[t] += v;
        __syncthreads();
    }
    off[t + 1] = sh[t];
    if (t == 0) off[0] = 0;
}

__global__ void k_fill(const int* dstA, const int* off, int* cur, int* csre) {
    int e = blockIdx.x * 256 + threadIdx.x;
    if (e >= ETOT) return;
    int d = dstA[e];
    int p = atomicAdd(&cur[d], 1);
    csre[off[d] + p] = e;
}

// ---------------- fp32 -> bf16 converts ----------------
__global__ void k_convA(const float* __restrict__ A, bf16_t* __restrict__ Ab,
                        int M, int K, int Kp) {
    int idx = blockIdx.x * 256 + threadIdx.x;
    if (idx >= M * Kp) return;
    int m = idx / Kp, k = idx % Kp;
    Ab[idx] = (k < K) ? (bf16_t)A[(size_t)m * K + k] : (bf16_t)0.f;
}

__global__ void k_convB(const float* __restrict__ B, bf16_t* __restrict__ Bt,
                        int K, int Nsub, int ldb, int Kp) {
    __shared__ float sh[32][33];
    int kt = blockIdx.y * 32, nt = blockIdx.x * 32;
    int tx = threadIdx.x % 32, ty = threadIdx.x / 32;
#pragma unroll
    for (int i = 0; i < 4; ++i) {
        int k = kt + ty + i * 8, n = nt + tx;
        sh[ty + i * 8][tx] = (k < K && n < Nsub) ? B[(size_t)k * ldb + n] : 0.f;
    }
    __syncthreads();
#pragma unroll
    for (int i = 0; i < 4; ++i) {
        int n = nt + ty + i * 8, k = kt + tx;
        if (n < Nsub) Bt[(size_t)n * Kp + k] = (bf16_t)sh[tx][ty + i * 8];
    }
}

// ---------------- bf16 MFMA GEMM ----------------
// C[M x Nsub] = Ab[M x Kp] @ Bt[Nsub x Kp]^T + bias; output fp32 or bf16 (obf).
#define LDP 40
__global__ __launch_bounds__(256) void k_gemm_bf16(
        const bf16_t* __restrict__ Ab, const bf16_t* __restrict__ Bt,
        const float* __restrict__ bias, void* __restrict__ Cm,
        int M, int Nsub, int Kp, int act, int obf) {
    __shared__ bf16_t As[128][LDP];
    __shared__ bf16_t Bs[128][LDP];
    int tid = threadIdx.x;
    int wave = tid >> 6, lane = tid & 63;
    int wm = (wave & 1) * 64, wn = (wave >> 1) * 64;
    int l16 = lane & 15, lq = lane >> 4;
    int m0 = blockIdx.y * 128, n0 = blockIdx.x * 128;

    f32x4 acc[4][4] = {};

    for (int k0 = 0; k0 < Kp; k0 += 32) {
        __syncthreads();
#pragma unroll
        for (int i = 0; i < 2; ++i) {
            int pp = tid + i * 256;
            int r = pp >> 2, kc = (pp & 3) * 8;
            bf16x8 va = *(const bf16x8*)(Ab + (size_t)(m0 + r) * Kp + k0 + kc);
            *(bf16x8*)(&As[r][kc]) = va;
            bf16x8 vb = {};
            if (n0 + r < Nsub)
                vb = *(const bf16x8*)(Bt + (size_t)(n0 + r) * Kp + k0 + kc);
            *(bf16x8*)(&Bs[r][kc]) = vb;
        }
        __syncthreads();
        bf16x8 af[4], bf[4];
#pragma unroll
        for (int mi = 0; mi < 4; ++mi)
            af[mi] = *(const bf16x8*)(&As[wm + mi * 16 + l16][lq * 8]);
#pragma unroll
        for (int ni = 0; ni < 4; ++ni)
            bf[ni] = *(const bf16x8*)(&Bs[wn + ni * 16 + l16][lq * 8]);
#pragma unroll
        for (int mi = 0; mi < 4; ++mi)
#pragma unroll
            for (int ni = 0; ni < 4; ++ni)
                acc[mi][ni] = __builtin_amdgcn_mfma_f32_16x16x32_bf16(
                    af[mi], bf[ni], acc[mi][ni], 0, 0, 0);
    }
#pragma unroll
    for (int mi = 0; mi < 4; ++mi)
#pragma unroll
        for (int ni = 0; ni < 4; ++ni)
#pragma unroll
            for (int r = 0; r < 4; ++r) {
                int row = m0 + wm + mi * 16 + lq * 4 + r;
                int col = n0 + wn + ni * 16 + l16;
                if (row < M && col < Nsub) {
                    float v = acc[mi][ni][r] + bias[col];
                    if (act && v < 0.f) v *= 0.01f;
                    if (obf) ((bf16_t*)Cm)[(size_t)row * Nsub + col] = (bf16_t)v;
                    else     ((float*)Cm)[(size_t)row * Nsub + col] = v;
                }
            }
}

// ------- fp32 GEMM (layer-1 / decoder-2): 64x64 tile, 4x4/thread, BK=16 -------
#define TM 64
#define TN 64
#define TK 16
__global__ __launch_bounds__(256) void k_gemm(
        const float* __restrict__ A, const float* __restrict__ B,
        const float* __restrict__ bias, void* __restrict__ Cm,
        int M, int Nsub, int K, int ldb, int act, int obf) {
    __shared__ float As[TK][TM];
    __shared__ float Bs[TK][TN];
    int tid = threadIdx.x;
    int tx = tid % 16, ty = tid / 16;
    int m0 = blockIdx.y * TM, n0 = blockIdx.x * TN;
    float acc[4][4] = {};
    for (int k0 = 0; k0 < K; k0 += TK) {
#pragma unroll
        for (int i = 0; i < 4; ++i) {
            int idx = tid * 4 + i;
            int m = idx >> 4, k = idx & 15;
            float v = 0.f;
            if (k0 + k < K && m0 + m < M) v = A[(size_t)(m0 + m) * K + k0 + k];
            As[k][m] = v;
        }
#pragma unroll
        for (int i = 0; i < 4; ++i) {
            int idx = tid * 4 + i;
            int k = idx >> 6, n = idx & 63;
            float v = 0.f;
            if (k0 + k < K && n0 + n < Nsub) v = B[(size_t)(k0 + k) * ldb + n0 + n];
            Bs[k][n] = v;
        }
        __syncthreads();
#pragma unroll
        for (int kk = 0; kk < TK; ++kk) {
            float4 a4 = *(const float4*)&As[kk][ty * 4];
            float4 b4 = *(const float4*)&Bs[kk][tx * 4];
            float af[4] = {a4.x, a4.y, a4.z, a4.w};
            float bf[4] = {b4.x, b4.y, b4.z, b4.w};
#pragma unroll
            for (int i = 0; i < 4; ++i)
#pragma unroll
                for (int j = 0; j < 4; ++j)
                    acc[i][j] += af[i] * bf[j];
        }
        __syncthreads();
    }
#pragma unroll
    for (int i = 0; i < 4; ++i) {
        int m = m0 + ty * 4 + i;
        if (m >= M) continue;
#pragma unroll
        for (int j = 0; j < 4; ++j) {
            int n = n0 + tx * 4 + j;
            if (n < Nsub) {
                float v = acc[i][j] + bias[n];
                if (act && v < 0.f) v *= 0.01f;
                if (obf) ((bf16_t*)Cm)[(size_t)m * Nsub + n] = (bf16_t)v;
                else     ((float*)Cm)[(size_t)m * Nsub + n] = v;
            }
        }
    }
}

__global__ void k_gemm_naive(const float* __restrict__ A, const float* __restrict__ B,
                             const float* __restrict__ bias, float* __restrict__ out,
                             int M, int N, int K, int act) {
    int idx = blockIdx.x * 256 + threadIdx.x;
    if (idx >= M * N) return;
    int m = idx / N, n = idx % N;
    float s = bias[n];
    for (int k = 0; k < K; ++k)
        s += A[(size_t)m * K + k] * B[(size_t)k * N + n];
    if (act && s < 0.f) s *= 0.01f;
    out[idx] = s;
}

// ------- attention scores: one wave per (edge, local head), bf16x4 loads -------
__global__ void k_score(const bf16_t* __restrict__ xl, const bf16_t* __restrict__ xr,
                        const float* __restrict__ att, const int* __restrict__ srcA,
                        const int* __restrict__ dstA, float* __restrict__ sc,
                        int C, int HG, int h0) {
    int wid = (blockIdx.x * 256 + threadIdx.x) >> 6;
    int lane = threadIdx.x & 63;
    if (wid >= ETOT * HG) return;
    int e = wid / HG, hl = wid % HG;
    int s = srcA[e], d = dstA[e];
    const bf16x4* pl = (const bf16x4*)(xl + ((size_t)s * HG + hl) * C);
    const bf16x4* pr = (const bf16x4*)(xr + ((size_t)d * HG + hl) * C);
    const float4* pa = (const float4*)(att + (size_t)(h0 + hl) * C);
    float acc = 0.f;
    int C4 = C >> 2;
    for (int c = lane; c < C4; c += 64) {
        bf16x4 a = pl[c], b = pr[c];
        float4 w = pa[c];
        float v;
        v = (float)a[0] + (float)b[0]; v = v > 0.f ? v : 0.2f * v; acc += v * w.x;
        v = (float)a[1] + (float)b[1]; v = v > 0.f ? v : 0.2f * v; acc += v * w.y;
        v = (float)a[2] + (float)b[2]; v = v > 0.f ? v : 0.2f * v; acc += v * w.z;
        v = (float)a[3] + (float)b[3]; v = v > 0.f ? v : 0.2f * v; acc += v * w.w;
    }
#pragma unroll
    for (int off = 32; off; off >>= 1) acc += __shfl_down(acc, off, 64);
    if (lane == 0) sc[(size_t)e * HH + h0 + hl] = acc;
}

// ---------------- softmax per (dst, head) over incoming edges -----------------
__global__ void k_softmax(const int* __restrict__ off, const int* __restrict__ csre,
                          float* __restrict__ sc, int HG, int h0) {
    int idx = blockIdx.x * 256 + threadIdx.x;
    if (idx >= NN * HG) return;
    int d = idx / HG, h = h0 + idx % HG;
    int b = off[d], en = off[d + 1];
    float m = -1e30f;
    for (int i = b; i < en; ++i) m = fmaxf(m, sc[(size_t)csre[i] * HH + h]);
    float ssum = 0.f;
    for (int i = b; i < en; ++i) ssum += expf(sc[(size_t)csre[i] * HH + h] - m);
    float inv = 1.f / ssum;
    for (int i = b; i < en; ++i) {
        size_t p = (size_t)csre[i] * HH + h;
        sc[p] = expf(sc[p] - m) * inv;
    }
}

// ------- aggregate: thread handles 4 channels, bf16x4 gathers, float4 z I/O -----
__global__ void k_aggregate(const bf16_t* __restrict__ xl, const float* __restrict__ sc,
                            const int* __restrict__ off, const int* __restrict__ csre,
                            const int* __restrict__ srcA, const float* __restrict__ bias,
                            float* __restrict__ z, int C, int HG, int h0,
                            int first, int last, int act) {
    int d = blockIdx.x;
    int c4 = blockIdx.y * 256 + threadIdx.x;
    int C4 = C >> 2;
    if (c4 >= C4) return;
    float4 acc = {0.f, 0.f, 0.f, 0.f};
    int b = off[d], en = off[d + 1];
    for (int i = b; i < en; ++i) {
        int e = csre[i];
        int s = srcA[e];
        const bf16x4* pl = (const bf16x4*)(xl + (size_t)s * HG * C) + c4;
        const float* pa = sc + (size_t)e * HH + h0;
        for (int hl = 0; hl < HG; ++hl) {
            bf16x4 vx = pl[(size_t)hl * C4];
            float w = pa[hl];
            acc.x += w * (float)vx[0];
            acc.y += w * (float)vx[1];
            acc.z += w * (float)vx[2];
            acc.w += w * (float)vx[3];
        }
    }
    float4* zp = (float4*)(z + (size_t)d * C) + c4;
    if (!first) {
        float4 prev = *zp;
        acc.x += prev.x; acc.y += prev.y; acc.z += prev.z; acc.w += prev.w;
    }
    if (last) {
        const float4 bz = *((const float4*)bias + c4);
        acc.x = acc.x * (1.f / 32.f) + bz.x;
        acc.y = acc.y * (1.f / 32.f) + bz.y;
        acc.z = acc.z * (1.f / 32.f) + bz.z;
        acc.w = acc.w * (1.f / 32.f) + bz.w;
        if (act) {
            acc.x = acc.x < 0.f ? acc.x * 0.01f : acc.x;
            acc.y = acc.y < 0.f ? acc.y * 0.01f : acc.y;
            acc.z = acc.z < 0.f ? acc.z * 0.01f : acc.z;
            acc.w = acc.w < 0.f ? acc.w * 0.01f : acc.w;
        }
    }
    *zp = acc;
}

// ---------------- host ----------------
extern "C" void kernel_launch(void* const* d_in, const int* in_sizes, int n_in,
                              void* d_out, int out_size, void* d_ws, size_t ws_size,
                              hipStream_t stream) {
    const float* x   = (const float*)d_in[0];
    const int* ei    = (const int*)d_in[1];
    const float* w1l = (const float*)d_in[2];  const float* b1l = (const float*)d_in[3];
    const float* w1r = (const float*)d_in[4];  const float* b1r = (const float*)d_in[5];
    const float* att1= (const float*)d_in[6];  const float* gb1 = (const float*)d_in[7];
    const float* w2l = (const float*)d_in[8];  const float* b2l = (const float*)d_in[9];
    const float* w2r = (const float*)d_in[10]; const float* b2r = (const float*)d_in[11];
    const float* att2= (const float*)d_in[12]; const float* gb2 = (const float*)d_in[13];
    const float* w3l = (const float*)d_in[14]; const float* b3l = (const float*)d_in[15];
    const float* w3r = (const float*)d_in[16]; const float* b3r = (const float*)d_in[17];
    const float* att3= (const float*)d_in[18]; const float* gb3 = (const float*)d_in[19];
    const float* dw1 = (const float*)d_in[20]; const float* db1 = (const float*)d_in[21];
    const float* dw2 = (const float*)d_in[22]; const float* db2 = (const float*)d_in[23];
    const float* dw3 = (const float*)d_in[24]; const float* db3 = (const float*)d_in[25];
    float* outp = (float*)d_out;

    char* p = (char*)d_ws;
    auto alloc = [&](size_t bytes) -> char* {
        char* r = p;
        p += (bytes + 255) & ~(size_t)255;
        return r;
    };
    float* sc   = (float*)alloc((size_t)ETOT * HH * 4);
    float* za   = (float*)alloc((size_t)NN * 1028 * 4);
    float* zb   = (float*)alloc((size_t)NN * 1028 * 4);
    bf16_t* Abf = (bf16_t*)alloc((size_t)NN * 1056 * 2);
    int*   ints = (int*)  alloc((size_t)(2 * NN + 16) * 4);
    int* cnt  = ints;
    int* cur  = ints + NN;
    int* flag = ints + 2 * NN;
    int* offp = (int*)alloc((size_t)(NN + 1) * 4);
    int* csre = (int*)alloc((size_t)ETOT * 4);
    int* srcA = (int*)alloc((size_t)ETOT * 4);
    int* dstA = (int*)alloc((size_t)ETOT * 4);
    size_t used = (size_t)(p - (char*)d_ws);
    size_t remain = (ws_size > used) ? (ws_size - used) : 0;
    char* chunk = p;

    k_zero_int<<<dim3((2 * NN + 16 + 255) / 256), dim3(256), 0, stream>>>(ints, 2 * NN + 16);
    k_detect<<<dim3((EE + 255) / 256), dim3(256), 0, stream>>>(ei, flag);
    k_edge_prep<<<dim3((ETOT + 255) / 256), dim3(256), 0, stream>>>(ei, flag, srcA, dstA, cnt);
    k_scan<<<dim3(1), dim3(NN), 0, stream>>>(cnt, offp);
    k_fill<<<dim3((ETOT + 255) / 256), dim3(256), 0, stream>>>(dstA, offp, cur, csre);

    struct Layer {
        const float* in; int cin; int C;
        const float *wl, *bl, *wr, *br, *att, *gb;
        float* zout; int act;
    };
    Layer L[3] = {
        { x,    4, 128,  w1l, b1l, w1r, b1r, att1, gb1, za, 1 },
        { za, 128, 512,  w2l, b2l, w2r, b2r, att2, gb2, zb, 1 },
        { zb, 512, 1028, w3l, b3l, w3r, b3r, att3, gb3, za, 0 },
    };
    auto al = [](size_t n) { return (n + 127) & ~(size_t)127; };

    for (int li = 0; li < 3; ++li) {
        int C = L[li].C, K = L[li].cin;
        bool mfma = (K >= 128);
        int Kp = (K + 31) & ~31;
        // per-head chunk bytes: xl + xr bf16 (+ Bt for mfma path)
        size_t perHG = 2ull * NN * C * 2 + (mfma ? (size_t)C * Kp * 2 : 0);
        int HG = 32;
        while (HG > 1 && (size_t)HG * perHG + 8192 > remain) HG >>= 1;
        int nchunk = HH / HG;
        bf16_t* xlc = (bf16_t*)chunk;
        bf16_t* xrc = xlc + al((size_t)NN * HG * C);
        bf16_t* Bt  = xrc + al((size_t)NN * HG * C);

        if (mfma)
            k_convA<<<dim3((NN * Kp + 255) / 256), dim3(256), 0, stream>>>(L[li].in, Abf, NN, K, Kp);

        for (int hg = 0; hg < nchunk; ++hg) {
            int h0 = hg * HG;
            int colOff = h0 * C;
            int Nsub = HG * C;
            if (mfma) {
                dim3 gc((Nsub + 31) / 32, Kp / 32);
                dim3 gg((Nsub + 127) / 128, NN / 128);
                k_convB<<<gc, dim3(256), 0, stream>>>(L[li].wl + colOff, Bt, K, Nsub, HH * C, Kp);
                k_gemm_bf16<<<gg, dim3(256), 0, stream>>>(Abf, Bt, L[li].bl + colOff, xlc, NN, Nsub, Kp, 0, 1);
                k_convB<<<gc, dim3(256), 0, stream>>>(L[li].wr + colOff, Bt, K, Nsub, HH * C, Kp);
                k_gemm_bf16<<<gg, dim3(256), 0, stream>>>(Abf, Bt, L[li].br + colOff, xrc, NN, Nsub, Kp, 0, 1);
            } else {
                dim3 gg((Nsub + TN - 1) / TN, (NN + TM - 1) / TM);
                k_gemm<<<gg, dim3(256), 0, stream>>>(L[li].in, L[li].wl + colOff, L[li].bl + colOff,
                                                     xlc, NN, Nsub, K, HH * C, 0, 1);
                k_gemm<<<gg, dim3(256), 0, stream>>>(L[li].in, L[li].wr + colOff, L[li].br + colOff,
                                                     xrc, NN, Nsub, K, HH * C, 0, 1);
            }
            int waves = ETOT * HG;
            k_score<<<dim3((waves * 64 + 255) / 256), dim3(256), 0, stream>>>(
                xlc, xrc, L[li].att, srcA, dstA, sc, C, HG, h0);
            k_softmax<<<dim3((NN * HG + 255) / 256), dim3(256), 0, stream>>>(offp, csre, sc, HG, h0);
            int C4 = C >> 2;
            dim3 ga(NN, (C4 + 255) / 256);
            k_aggregate<<<ga, dim3(256), 0, stream>>>(xlc, sc, offp, csre, srcA, L[li].gb,
                                                      L[li].zout, C, HG, h0,
                                                      hg == 0, hg == nchunk - 1, L[li].act);
        }
    }

    // ---- decoder ----
    {
        int K = 1028, Kp = 1056, Nsub = 512;
        bf16_t* Bt = (bf16_t*)chunk;
        k_convA<<<dim3((NN * Kp + 255) / 256), dim3(256), 0, stream>>>(za, Abf, NN, K, Kp);
        k_convB<<<dim3(Nsub / 32, Kp / 32), dim3(256), 0, stream>>>(dw1, Bt, K, Nsub, Nsub, Kp);
        k_gemm_bf16<<<dim3(Nsub / 128, NN / 128), dim3(256), 0, stream>>>(Abf, Bt, db1, zb, NN, Nsub, Kp, 1, 0);
    }
    k_gemm<<<dim3(128 / TN, NN / TM), dim3(256), 0, stream>>>(zb, dw2, db2, za, NN, 128, 512, 128, 1, 0);
    k_gemm_naive<<<dim3((NN * 2 + 255) / 256), dim3(256), 0, stream>>>(za, dw3, db3, outp, NN, 2, 128, 0);
}